// Round 13
// baseline (197.104 us; speedup 1.0000x reference)
//
#include <hip/hip_runtime.h>

typedef unsigned short u16;
typedef unsigned int u32;
typedef __bf16 bf16x4 __attribute__((ext_vector_type(4)));
typedef __bf16 bf16x8 __attribute__((ext_vector_type(8)));
typedef float f32x4 __attribute__((ext_vector_type(4)));
typedef u32 u32x4 __attribute__((ext_vector_type(4)));

struct __align__(4) U16x2 { u16 x, y; };
struct __align__(8) U16x4 { u16 x, y, z, w; };

#define DEV static __device__ __forceinline__

extern "C" __device__ float __ocml_exp2_f32(float);
#if __has_builtin(__builtin_amdgcn_exp2f)
#define EXP2(x) __builtin_amdgcn_exp2f(x)
#else
#define EXP2(x) __ocml_exp2_f32(x)
#endif

DEV u16 f2bf(float f) {
  __bf16 h = (__bf16)f;
  return __builtin_bit_cast(u16, h);
}
DEV u32 pk2bf(float lo, float hi) { return (u32)f2bf(lo) | ((u32)f2bf(hi) << 16); }

DEV void gload16(const void* g, void* l) {
  __builtin_amdgcn_global_load_lds((const __attribute__((address_space(1))) char*)g,
                                   (__attribute__((address_space(3))) char*)l, 16, 0, 0);
}

DEV f32x4 mfma16(bf16x8 a, bf16x8 b, f32x4 c) {
  return __builtin_amdgcn_mfma_f32_16x16x32_bf16(a, b, c, 0, 0, 0);
}

// ---------------------------------------------------------------------------
// Merged prep: one launch does x fp32->bf16 (blocks [0,8192)) and the four
// weight transpose+converts (blocks [8192,18432)). Branch is block-uniform.
__global__ __launch_bounds__(256) void prep(const float* __restrict__ x,
                                            const float* __restrict__ wq,
                                            const float* __restrict__ wk,
                                            const float* __restrict__ wv,
                                            const float* __restrict__ wo,
                                            u16* __restrict__ xb,
                                            u16* __restrict__ wqkvT,
                                            u16* __restrict__ woT) {
  __shared__ float t[32][33];
  int id = blockIdx.x;
  int tx = threadIdx.x, ty = threadIdx.y;
  if (id < 8192) {  // cvt_x: 4 fp32 -> 4 bf16 per thread
    int i = id * 256 + ty * 32 + tx;
    float4 v = ((const float4*)x)[i];
    U16x4 o;
    o.x = f2bf(v.x); o.y = f2bf(v.y); o.z = f2bf(v.z); o.w = f2bf(v.w);
    ((U16x4*)xb)[i] = o;
    return;
  }
  id -= 8192;
  const float* src;
  u16* dst;
  int C, nOff, gx;
  if (id < 4096)      { src = wq; dst = wqkvT; C = 2048; nOff = 0;    gx = 64; }
  else if (id < 5120) { id -= 4096; src = wk; dst = wqkvT; C = 512; nOff = 2048; gx = 16; }
  else if (id < 6144) { id -= 5120; src = wv; dst = wqkvT; C = 512; nOff = 2560; gx = 16; }
  else                { id -= 6144; src = wo; dst = woT;   C = 2048; nOff = 0;   gx = 64; }
  int bx = id % gx, by = id / gx;
#pragma unroll
  for (int j = 0; j < 4; ++j)
    t[ty + 8 * j][tx] = src[(size_t)(by * 32 + ty + 8 * j) * C + bx * 32 + tx];
  __syncthreads();
#pragma unroll
  for (int j = 0; j < 4; ++j)
    dst[(size_t)(nOff + bx * 32 + ty + 8 * j) * 2048 + by * 32 + tx] = f2bf(t[tx][ty + 8 * j]);
}

// ---------------------------------------------------------------------------
// QKV GEMM with fused RoPE + direct V-transpose epilogue.
// C = A[4096][2048] * BT[3072][2048]^T. Routes: col<2048 -> Q (roped,
// pre-scaled 0.125*log2e), col<2560 -> K (roped), else -> Vt[(b*8+kh)*64+d][s]
// directly (4 consecutive s per lane = one 8B store). No grid swizzle (R11).
__global__ __launch_bounds__(256, 2) void gemm_qkv(const u16* __restrict__ A,
                                                   const u16* __restrict__ BT,
                                                   const float* __restrict__ fc,
                                                   const float* __restrict__ fs,
                                                   u16* __restrict__ Qo,
                                                   u16* __restrict__ Ko,
                                                   u16* __restrict__ Vt) {
  __shared__ __align__(16) char smem[65536];
  const int tid = threadIdx.x;
  const int lane = tid & 63;
  const int wm = (tid >> 7) & 1, wn = (tid >> 6) & 1;
  const int tm = blockIdx.y, tn = blockIdx.x;
  const int K = 2048, Kb = 4096;

  f32x4 acc[4][4];
#pragma unroll
  for (int i = 0; i < 4; ++i)
#pragma unroll
    for (int j = 0; j < 4; ++j) acc[i][j] = (f32x4){0.f, 0.f, 0.f, 0.f};

  const char* Ag = (const char*)A + (size_t)tm * 128 * Kb;
  const char* Bg = (const char*)BT + (size_t)tn * 128 * Kb;

  auto stage = [&](int buf, int t) {
#pragma unroll
    for (int i = 0; i < 4; ++i) {
      int vt = i * 256 + tid;
      int row = vt >> 3;
      int cb = (((vt & 7) << 4) ^ ((row & 7) << 4));
      gload16(Ag + (size_t)row * Kb + t * 128 + cb, smem + buf * 16384 + vt * 16);
      gload16(Bg + (size_t)row * Kb + t * 128 + cb, smem + 32768 + buf * 16384 + vt * 16);
    }
  };

  stage(0, 0);
  int cur = 0;
  const int NT = K >> 6;
  for (int t = 0; t < NT; ++t) {
    __syncthreads();
    if (t + 1 < NT) stage(cur ^ 1, t + 1);
    const char* As = smem + cur * 16384;
    const char* Bs = smem + 32768 + cur * 16384;
#pragma unroll
    for (int ks = 0; ks < 2; ++ks) {
      bf16x8 a[4], b[4];
#pragma unroll
      for (int mf = 0; mf < 4; ++mf) {
        int row = wm * 64 + mf * 16 + (lane & 15);
        int cb = (ks * 64 + ((lane >> 4) << 4)) ^ ((row & 7) << 4);
        a[mf] = *(const bf16x8*)(As + row * 128 + cb);
      }
#pragma unroll
      for (int nf = 0; nf < 4; ++nf) {
        int row = wn * 64 + nf * 16 + (lane & 15);
        int cb = (ks * 64 + ((lane >> 4) << 4)) ^ ((row & 7) << 4);
        b[nf] = *(const bf16x8*)(Bs + row * 128 + cb);
      }
#pragma unroll
      for (int mf = 0; mf < 4; ++mf)
#pragma unroll
        for (int nf = 0; nf < 4; ++nf) acc[mf][nf] = mfma16(a[mf], b[nf], acc[mf][nf]);
    }
    cur ^= 1;
  }

  const float QS = 0.18033688011112042f;  // 0.125 * log2(e)
#pragma unroll
  for (int mf = 0; mf < 4; ++mf) {
    int row0 = tm * 128 + wm * 64 + mf * 16 + ((lane >> 4) << 2);
    int bb = row0 >> 11, s0 = row0 & 2047;
#pragma unroll
    for (int nf = 0; nf < 4; ++nf) {
      int col = tn * 128 + wn * 64 + nf * 16 + (lane & 15);
      if (col < 2560) {  // Q or K: apply RoPE (exact R11 path)
        int d = col & 63, d2 = d >> 1;
        bool ev = !(col & 1);
        bool isQ = (col < 2048);
        int hh = isQ ? (col >> 6) : ((col - 2048) >> 6);
#pragma unroll
        for (int r = 0; r < 4; ++r) {
          int s = s0 + r;
          float v = acc[mf][nf][r];
          float p = __shfl_xor(v, 1, 64);
          float c = fc[s * 32 + d2], sn = fs[s * 32 + d2];
          if (isQ) { c *= QS; sn *= QS; }
          float o = ev ? (v * c - p * sn) : (v * c + p * sn);
          if (isQ)
            Qo[((size_t)(bb * 32 + hh) * 2048 + s) * 64 + d] = f2bf(o);
          else
            Ko[((size_t)(bb * 8 + hh) * 2048 + s) * 64 + d] = f2bf(o);
        }
      } else {  // V: write transposed directly (4 consecutive s = 8B store)
        int dv = col - 2560;
        int khl = dv >> 6, dd = dv & 63;
        U16x4 o;
        o.x = f2bf(acc[mf][nf][0]);
        o.y = f2bf(acc[mf][nf][1]);
        o.z = f2bf(acc[mf][nf][2]);
        o.w = f2bf(acc[mf][nf][3]);
        *(U16x4*)(Vt + (size_t)((bb * 8 + khl) * 64 + dd) * 2048 + s0) = o;
      }
    }
  }
}

// ---------------------------------------------------------------------------
// C[M][N] = A[M][K] * BT[N][K]^T  (bf16 in, float out) -- WO GEMM (exact R11).
__global__ __launch_bounds__(256, 2) void gemm_bt(const u16* __restrict__ A,
                                                  const u16* __restrict__ BT,
                                                  float* __restrict__ C,
                                                  int M, int N, int K) {
  __shared__ __align__(16) char smem[65536];
  const int tid = threadIdx.x;
  const int lane = tid & 63;
  const int wm = (tid >> 7) & 1, wn = (tid >> 6) & 1;
  const int tm = blockIdx.y, tn = blockIdx.x;
  const int Kb = K * 2;

  f32x4 acc[4][4];
#pragma unroll
  for (int i = 0; i < 4; ++i)
#pragma unroll
    for (int j = 0; j < 4; ++j) acc[i][j] = (f32x4){0.f, 0.f, 0.f, 0.f};

  const char* Ag = (const char*)A + (size_t)tm * 128 * Kb;
  const char* Bg = (const char*)BT + (size_t)tn * 128 * Kb;

  auto stage = [&](int buf, int t) {
#pragma unroll
    for (int i = 0; i < 4; ++i) {
      int vt = i * 256 + tid;
      int row = vt >> 3;
      int cb = (((vt & 7) << 4) ^ ((row & 7) << 4));
      gload16(Ag + (size_t)row * Kb + t * 128 + cb, smem + buf * 16384 + vt * 16);
      gload16(Bg + (size_t)row * Kb + t * 128 + cb, smem + 32768 + buf * 16384 + vt * 16);
    }
  };

  stage(0, 0);
  int cur = 0;
  const int NT = K >> 6;
  for (int t = 0; t < NT; ++t) {
    __syncthreads();
    if (t + 1 < NT) stage(cur ^ 1, t + 1);
    const char* As = smem + cur * 16384;
    const char* Bs = smem + 32768 + cur * 16384;
#pragma unroll
    for (int ks = 0; ks < 2; ++ks) {
      bf16x8 a[4], b[4];
#pragma unroll
      for (int mf = 0; mf < 4; ++mf) {
        int row = wm * 64 + mf * 16 + (lane & 15);
        int cb = (ks * 64 + ((lane >> 4) << 4)) ^ ((row & 7) << 4);
        a[mf] = *(const bf16x8*)(As + row * 128 + cb);
      }
#pragma unroll
      for (int nf = 0; nf < 4; ++nf) {
        int row = wn * 64 + nf * 16 + (lane & 15);
        int cb = (ks * 64 + ((lane >> 4) << 4)) ^ ((row & 7) << 4);
        b[nf] = *(const bf16x8*)(Bs + row * 128 + cb);
      }
#pragma unroll
      for (int mf = 0; mf < 4; ++mf)
#pragma unroll
        for (int nf = 0; nf < 4; ++nf) acc[mf][nf] = mfma16(a[mf], b[nf], acc[mf][nf]);
    }
    cur ^= 1;
  }
#pragma unroll
  for (int mf = 0; mf < 4; ++mf) {
    int row0 = tm * 128 + wm * 64 + mf * 16 + ((lane >> 4) << 2);
#pragma unroll
    for (int nf = 0; nf < 4; ++nf) {
      int col = tn * 128 + wn * 64 + nf * 16 + (lane & 15);
#pragma unroll
      for (int r = 0; r < 4; ++r)
        C[(size_t)(row0 + r) * N + col] = acc[mf][nf][r];
    }
  }
}

// ---------------------------------------------------------------------------
// Causal GQA flash attention -- EXACT R11 kernel (proven, 75.2 us):
// dual-tile waves, swapped QK^T, in-register P, PV via K=32 MFMA through a
// kv-permuted K tile, KVBLK=32, ones-column MFMA for l, fully resident
// (2048 blocks x 128 thr x 16KB = 8 blocks/CU, perfectly balanced).
__global__ __launch_bounds__(128, 4) void attn(const u16* __restrict__ Q,
                                               const u16* __restrict__ Kt,
                                               const u16* __restrict__ Vt,
                                               u16* __restrict__ O) {
  __shared__ __align__(16) char smem[16384];  // per buf: K 4KB + V 4KB

  const int tid = threadIdx.x, lane = tid & 63, w = tid >> 6;  // w in {0,1}
  const int q15 = lane & 15, g = lane >> 4;
  const int bx = blockIdx.x, h = blockIdx.y, b = blockIdx.z;
  const int kh = h >> 2;
  const int QT0 = 63 - bx, QT1 = bx;  // heavy, light q-tiles (32 rows each)

  const char* Qg = (const char*)(Q + ((size_t)(b * 32 + h) * 2048) * 64);
  const char* Kg = (const char*)(Kt + ((size_t)(b * 8 + kh) * 2048 * 64));
  const char* Vg = (const char*)(Vt + ((size_t)(b * 8 + kh) * 64 * 2048));

  u32x4 onesW;
  onesW.x = onesW.y = onesW.z = onesW.w = 0x3F803F80u;  // bf16 1.0 x8
  const bf16x8 ONES = __builtin_bit_cast(bf16x8, onesW);

  // Q fragments (B-operand of swapped QK^T), both tiles
  bf16x8 qf0[2], qf1[2];
#pragma unroll
  for (int ks = 0; ks < 2; ++ks) {
    int r0 = QT0 * 32 + w * 16 + q15;
    int r1 = QT1 * 32 + w * 16 + q15;
    qf0[ks] = *(const bf16x8*)(Qg + (size_t)r0 * 128 + ks * 64 + (g << 4));
    qf1[ks] = *(const bf16x8*)(Qg + (size_t)r1 * 128 + ks * 64 + (g << 4));
  }

  f32x4 acc0[4], acc1[4], accl0, accl1;
#pragma unroll
  for (int j = 0; j < 4; ++j) {
    acc0[j] = (f32x4){0.f, 0.f, 0.f, 0.f};
    acc1[j] = (f32x4){0.f, 0.f, 0.f, 0.f};
  }
  accl0 = (f32x4){0.f, 0.f, 0.f, 0.f};
  accl1 = (f32x4){0.f, 0.f, 0.f, 0.f};
  float m0 = -1e30f, m1 = -1e30f;
  const f32x4 FZ = (f32x4){0.f, 0.f, 0.f, 0.f};

  auto stageKV = [&](int buf, int kt) {
#pragma unroll
    for (int i = 0; i < 2; ++i) {
      int vt = i * 128 + tid;  // 0..255
      // K: LDS row rho holds global kv row kappa(rho) = 8g'+4nf'+r'
      int rho = vt >> 3, ck = vt & 7;
      int kap = ((rho & 12) << 1) + ((rho & 16) >> 2) + (rho & 3);
      gload16(Kg + (size_t)(kt * 32 + kap) * 128 + (((ck ^ rho) & 7) << 4),
              smem + buf * 8192 + vt * 16);
      // V: natural kv order, 64 d-rows x 64B, chunk swizzle ^((d>>1)&3)
      int d = vt >> 2, cv = vt & 3;
      gload16(Vg + (size_t)d * 4096 + kt * 64 + (((cv ^ (d >> 1)) & 3) << 4),
              smem + buf * 8192 + 4096 + vt * 16);
    }
  };

  stageKV(0, 0);
  int cur = 0;
  const int nkt = QT0 + 1;
  for (int kt = 0; kt < nkt; ++kt) {
    __syncthreads();  // KV[cur] staged (compiler drains vmcnt before barrier)
    if (kt + 1 < nkt) stageKV(cur ^ 1, kt + 1);
    const char* Ks = smem + cur * 8192;
    const char* Vs = smem + cur * 8192 + 4096;
    const bool la = (kt <= QT1);  // light tile active

    // K fragments (A-operand), shared by both tiles
    bf16x8 kf[2][2];  // [ks][nf]
#pragma unroll
    for (int ks = 0; ks < 2; ++ks)
#pragma unroll
      for (int nf = 0; nf < 2; ++nf) {
        int r = nf * 16 + q15;
        int c = (4 * ks + g) ^ (r & 7);
        kf[ks][nf] = *(const bf16x8*)(Ks + r * 128 + (c << 4));
      }

    // swapped QK^T: lane holds S[q = Qt*32+w*16+q15][k = kt*32 + 8g+4nf+r]
    f32x4 st0[2], st1[2];
    __builtin_amdgcn_s_setprio(1);
#pragma unroll
    for (int nf = 0; nf < 2; ++nf) {
      st0[nf] = mfma16(kf[0][nf], qf0[0], FZ);
      st0[nf] = mfma16(kf[1][nf], qf0[1], st0[nf]);
    }
    if (la) {
#pragma unroll
      for (int nf = 0; nf < 2; ++nf) {
        st1[nf] = mfma16(kf[0][nf], qf1[0], FZ);
        st1[nf] = mfma16(kf[1][nf], qf1[1], st1[nf]);
      }
    }
    __builtin_amdgcn_s_setprio(0);

    // causal mask on each tile's diagonal step (k = kt*32 + 8g + 4nf + r)
    if (kt == QT0) {
      int qg = QT0 * 32 + w * 16 + q15;
#pragma unroll
      for (int nf = 0; nf < 2; ++nf)
#pragma unroll
        for (int r = 0; r < 4; ++r) {
          int kg = kt * 32 + 8 * g + 4 * nf + r;
          if (kg > qg) st0[nf][r] = -1e30f;
        }
    }
    if (la && kt == QT1) {
      int qg = QT1 * 32 + w * 16 + q15;
#pragma unroll
      for (int nf = 0; nf < 2; ++nf)
#pragma unroll
        for (int r = 0; r < 4; ++r) {
          int kg = kt * 32 + 8 * g + 4 * nf + r;
          if (kg > qg) st1[nf][r] = -1e30f;
        }
    }

    // softmax (exp2 domain): zero cross-lane ops in the common path; l is
    // accumulated by the ones-column MFMA in the PV step below.
    bf16x8 pa0, pa1;
#pragma unroll
    for (int t = 0; t < 2; ++t) {
      if (t == 1 && !la) break;
      f32x4* st = (t == 0) ? st0 : st1;
      float& m_r = (t == 0) ? m0 : m1;
      f32x4* accT = (t == 0) ? acc0 : acc1;
      f32x4& acclT = (t == 0) ? accl0 : accl1;

      // per-lane max over this lane's 8 S values + m_r, 3-ary for v_max3
      float vm = fmaxf(fmaxf(fmaxf(fmaxf(st[0][0], st[0][1]), st[0][2]),
                             fmaxf(fmaxf(st[0][3], st[1][0]), st[1][1])),
                       fmaxf(fmaxf(st[1][2], st[1][3]), m_r));
      // T13 defer-rescale: __all on per-lane max == check on the global max.
      if (!__all(vm - m_r <= 8.0f)) {
        vm = fmaxf(vm, __shfl_xor(vm, 16, 64));
        vm = fmaxf(vm, __shfl_xor(vm, 32, 64));
        float cr = EXP2(m_r - vm);
        m_r = vm;
        float cra[4];
#pragma unroll
        for (int r = 0; r < 4; ++r) cra[r] = __shfl(cr, 4 * g + r, 64);
#pragma unroll
        for (int nfd = 0; nfd < 4; ++nfd)
#pragma unroll
          for (int r = 0; r < 4; ++r) accT[nfd][r] *= cra[r];
#pragma unroll
        for (int r = 0; r < 4; ++r) acclT[r] *= cra[r];
      }
      // P = exp2(S - m); pack into the K=32 A-fragment (k = 8g + 4nf + r)
      u32x4 W;
      W.x = pk2bf(EXP2(st[0][0] - m_r), EXP2(st[0][1] - m_r));
      W.y = pk2bf(EXP2(st[0][2] - m_r), EXP2(st[0][3] - m_r));
      W.z = pk2bf(EXP2(st[1][0] - m_r), EXP2(st[1][1] - m_r));
      W.w = pk2bf(EXP2(st[1][2] - m_r), EXP2(st[1][3] - m_r));
      if (t == 0) pa0 = __builtin_bit_cast(bf16x8, W);
      else pa1 = __builtin_bit_cast(bf16x8, W);
    }

    // PV via K=32 MFMA: B-frag = V^T[d = nfd*16+q15][k = kt*32 + 8g..8g+7];
    // plus one ones-column MFMA per tile to accumulate l in acc layout.
#pragma unroll
    for (int nfd = 0; nfd < 4; ++nfd) {
      int d = nfd * 16 + q15;
      int c = (g ^ (d >> 1)) & 3;
      bf16x8 vb = *(const bf16x8*)(Vs + d * 64 + (c << 4));
      __builtin_amdgcn_s_setprio(1);
      acc0[nfd] = mfma16(pa0, vb, acc0[nfd]);
      if (la) acc1[nfd] = mfma16(pa1, vb, acc1[nfd]);
      __builtin_amdgcn_s_setprio(0);
    }
    __builtin_amdgcn_s_setprio(1);
    accl0 = mfma16(pa0, ONES, accl0);
    if (la) accl1 = mfma16(pa1, ONES, accl1);
    __builtin_amdgcn_s_setprio(0);
    cur ^= 1;
  }

  // epilogue: l is already per-lane in acc row layout -- no shuffles.
#pragma unroll
  for (int t = 0; t < 2; ++t) {
    f32x4* accT = (t == 0) ? acc0 : acc1;
    f32x4 acclT = (t == 0) ? accl0 : accl1;
    int qt = (t == 0) ? QT0 : QT1;
    u16* Og = O + ((size_t)(b * 2048 + qt * 32 + w * 16) * 2048 + h * 64);
#pragma unroll
    for (int r = 0; r < 4; ++r) {
      float li = 1.f / acclT[r];
#pragma unroll
      for (int nfd = 0; nfd < 4; ++nfd)
        Og[(size_t)(4 * g + r) * 2048 + nfd * 16 + q15] = f2bf(accT[nfd][r] * li);
    }
  }
}

// ---------------------------------------------------------------------------
extern "C" void kernel_launch(void* const* d_in, const int* in_sizes, int n_in,
                              void* d_out, int out_size, void* d_ws, size_t ws_size,
                              hipStream_t stream) {
  const float* x = (const float*)d_in[0];
  const float* fc = (const float*)d_in[1];
  const float* fs = (const float*)d_in[2];
  const float* wq = (const float*)d_in[3];
  const float* wk = (const float*)d_in[4];
  const float* wv = (const float*)d_in[5];
  const float* wo = (const float*)d_in[6];
  float* out = (float*)d_out;
  char* ws = (char*)d_ws;

  // Workspace layout (64 MB):
  u16* xb    = (u16*)(ws);                 // [4096][2048] 16 MB (reused as attn O)
  u16* Qb    = (u16*)(ws + 16777216);      // [2][32][2048][64] 16 MB (roped, exp2-scaled)
  u16* Kb    = (u16*)(ws + 33554432);      // [2][8][2048][64]   4 MB (roped)
  u16* Vtb   = (u16*)(ws + 41943040);      // [2][8][64][2048]   4 MB (written by gemm_qkv)
  u16* woT   = (u16*)(ws + 46137344);      // [2048][2048]       8 MB
  u16* wqkvT = (u16*)(ws + 54525952);      // [3072][2048]      12 MB
  u16* Obuf = xb;

  dim3 tb(32, 8);
  prep<<<dim3(18432), tb, 0, stream>>>(x, wq, wk, wv, wo, xb, wqkvT, woT);
  gemm_qkv<<<dim3(24, 32), dim3(256), 0, stream>>>(xb, wqkvT, fc, fs, Qb, Kb, Vtb);
  attn<<<dim3(32, 32, 2), dim3(128), 0, stream>>>(Qb, Kb, Vtb, Obuf);
  gemm_bt<<<dim3(16, 32), dim3(256), 0, stream>>>(Obuf, woT, out, 4096, 2048, 2048);
}

// Round 15
// 189.516 us; speedup vs baseline: 1.0400x; 1.0400x over previous
//
#include <hip/hip_runtime.h>

typedef unsigned short u16;
typedef unsigned int u32;
typedef __bf16 bf16x4 __attribute__((ext_vector_type(4)));
typedef __bf16 bf16x8 __attribute__((ext_vector_type(8)));
typedef float f32x4 __attribute__((ext_vector_type(4)));
typedef u32 u32x4 __attribute__((ext_vector_type(4)));

struct __align__(4) U16x2 { u16 x, y; };
struct __align__(8) U16x4 { u16 x, y, z, w; };

#define DEV static __device__ __forceinline__

extern "C" __device__ float __ocml_exp2_f32(float);
#if __has_builtin(__builtin_amdgcn_exp2f)
#define EXP2(x) __builtin_amdgcn_exp2f(x)
#else
#define EXP2(x) __ocml_exp2_f32(x)
#endif

DEV u16 f2bf(float f) {
  __bf16 h = (__bf16)f;
  return __builtin_bit_cast(u16, h);
}
DEV u32 pk2bf(float lo, float hi) { return (u32)f2bf(lo) | ((u32)f2bf(hi) << 16); }

DEV void gload16(const void* g, void* l) {
  __builtin_amdgcn_global_load_lds((const __attribute__((address_space(1))) char*)g,
                                   (__attribute__((address_space(3))) char*)l, 16, 0, 0);
}

DEV f32x4 mfma16(bf16x8 a, bf16x8 b, f32x4 c) {
  return __builtin_amdgcn_mfma_f32_16x16x32_bf16(a, b, c, 0, 0, 0);
}

// ---------------------------------------------------------------------------
// Merged prep: one launch does x fp32->bf16 (blocks [0,8192)) and the four
// weight transpose+converts (blocks [8192,18432)). Branch is block-uniform.
__global__ __launch_bounds__(256) void prep(const float* __restrict__ x,
                                            const float* __restrict__ wq,
                                            const float* __restrict__ wk,
                                            const float* __restrict__ wv,
                                            const float* __restrict__ wo,
                                            u16* __restrict__ xb,
                                            u16* __restrict__ wqkvT,
                                            u16* __restrict__ woT) {
  __shared__ float t[32][33];
  int id = blockIdx.x;
  int tx = threadIdx.x, ty = threadIdx.y;
  if (id < 8192) {  // cvt_x: 4 fp32 -> 4 bf16 per thread
    int i = id * 256 + ty * 32 + tx;
    float4 v = ((const float4*)x)[i];
    U16x4 o;
    o.x = f2bf(v.x); o.y = f2bf(v.y); o.z = f2bf(v.z); o.w = f2bf(v.w);
    ((U16x4*)xb)[i] = o;
    return;
  }
  id -= 8192;
  const float* src;
  u16* dst;
  int C, nOff, gx;
  if (id < 4096)      { src = wq; dst = wqkvT; C = 2048; nOff = 0;    gx = 64; }
  else if (id < 5120) { id -= 4096; src = wk; dst = wqkvT; C = 512; nOff = 2048; gx = 16; }
  else if (id < 6144) { id -= 5120; src = wv; dst = wqkvT; C = 512; nOff = 2560; gx = 16; }
  else                { id -= 6144; src = wo; dst = woT;   C = 2048; nOff = 0;   gx = 64; }
  int bx = id % gx, by = id / gx;
#pragma unroll
  for (int j = 0; j < 4; ++j)
    t[ty + 8 * j][tx] = src[(size_t)(by * 32 + ty + 8 * j) * C + bx * 32 + tx];
  __syncthreads();
#pragma unroll
  for (int j = 0; j < 4; ++j)
    dst[(size_t)(nOff + bx * 32 + ty + 8 * j) * 2048 + by * 32 + tx] = f2bf(t[tx][ty + 8 * j]);
}

// ---------------------------------------------------------------------------
// QKV GEMM with fused RoPE + direct V-transpose epilogue.
// C = A[4096][2048] * BT[3072][2048]^T. Block split is clean: tn<20 -> Q/K
// (roped; Q pre-scaled 0.125*log2e), tn>=20 -> V, transposed through LDS
// (smem is free after the K-loop) and stored coalesced to Vt[(b*8+kh)*64+d][s].
__global__ __launch_bounds__(256, 2) void gemm_qkv(const u16* __restrict__ A,
                                                   const u16* __restrict__ BT,
                                                   const float* __restrict__ fc,
                                                   const float* __restrict__ fs,
                                                   u16* __restrict__ Qo,
                                                   u16* __restrict__ Ko,
                                                   u16* __restrict__ Vt) {
  __shared__ __align__(16) char smem[65536];
  const int tid = threadIdx.x;
  const int lane = tid & 63;
  const int wm = (tid >> 7) & 1, wn = (tid >> 6) & 1;
  const int tm = blockIdx.y, tn = blockIdx.x;
  const int K = 2048, Kb = 4096;

  f32x4 acc[4][4];
#pragma unroll
  for (int i = 0; i < 4; ++i)
#pragma unroll
    for (int j = 0; j < 4; ++j) acc[i][j] = (f32x4){0.f, 0.f, 0.f, 0.f};

  const char* Ag = (const char*)A + (size_t)tm * 128 * Kb;
  const char* Bg = (const char*)BT + (size_t)tn * 128 * Kb;

  auto stage = [&](int buf, int t) {
#pragma unroll
    for (int i = 0; i < 4; ++i) {
      int vt = i * 256 + tid;
      int row = vt >> 3;
      int cb = (((vt & 7) << 4) ^ ((row & 7) << 4));
      gload16(Ag + (size_t)row * Kb + t * 128 + cb, smem + buf * 16384 + vt * 16);
      gload16(Bg + (size_t)row * Kb + t * 128 + cb, smem + 32768 + buf * 16384 + vt * 16);
    }
  };

  stage(0, 0);
  int cur = 0;
  const int NT = K >> 6;
  for (int t = 0; t < NT; ++t) {
    __syncthreads();
    if (t + 1 < NT) stage(cur ^ 1, t + 1);
    const char* As = smem + cur * 16384;
    const char* Bs = smem + 32768 + cur * 16384;
#pragma unroll
    for (int ks = 0; ks < 2; ++ks) {
      bf16x8 a[4], b[4];
#pragma unroll
      for (int mf = 0; mf < 4; ++mf) {
        int row = wm * 64 + mf * 16 + (lane & 15);
        int cb = (ks * 64 + ((lane >> 4) << 4)) ^ ((row & 7) << 4);
        a[mf] = *(const bf16x8*)(As + row * 128 + cb);
      }
#pragma unroll
      for (int nf = 0; nf < 4; ++nf) {
        int row = wn * 64 + nf * 16 + (lane & 15);
        int cb = (ks * 64 + ((lane >> 4) << 4)) ^ ((row & 7) << 4);
        b[nf] = *(const bf16x8*)(Bs + row * 128 + cb);
      }
#pragma unroll
      for (int mf = 0; mf < 4; ++mf)
#pragma unroll
        for (int nf = 0; nf < 4; ++nf) acc[mf][nf] = mfma16(a[mf], b[nf], acc[mf][nf]);
    }
    cur ^= 1;
  }

  if (tn < 20) {  // Q or K tile: RoPE epilogue (exact R11/R13 path)
    const float QS = 0.18033688011112042f;  // 0.125 * log2(e)
#pragma unroll
    for (int mf = 0; mf < 4; ++mf) {
      int row0 = tm * 128 + wm * 64 + mf * 16 + ((lane >> 4) << 2);
      int bb = row0 >> 11, s0 = row0 & 2047;
#pragma unroll
      for (int nf = 0; nf < 4; ++nf) {
        int col = tn * 128 + wn * 64 + nf * 16 + (lane & 15);
        int d = col & 63, d2 = d >> 1;
        bool ev = !(col & 1);
        bool isQ = (col < 2048);
        int hh = isQ ? (col >> 6) : ((col - 2048) >> 6);
#pragma unroll
        for (int r = 0; r < 4; ++r) {
          int s = s0 + r;
          float v = acc[mf][nf][r];
          float p = __shfl_xor(v, 1, 64);
          float c = fc[s * 32 + d2], sn = fs[s * 32 + d2];
          if (isQ) { c *= QS; sn *= QS; }
          float o = ev ? (v * c - p * sn) : (v * c + p * sn);
          if (isQ)
            Qo[((size_t)(bb * 32 + hh) * 2048 + s) * 64 + d] = f2bf(o);
          else
            Ko[((size_t)(bb * 8 + hh) * 2048 + s) * 64 + d] = f2bf(o);
        }
      }
    }
  } else {  // V tile: transpose 128(dv) x 128(s) through LDS, store coalesced
    u16* T = (u16*)smem;  // [128][136] u16 = 34,816 B (pad 136: 16B-aligned rows)
    __syncthreads();  // all waves done reading staged A/B from smem
#pragma unroll
    for (int mf = 0; mf < 4; ++mf) {
      int sl0 = wm * 64 + mf * 16 + ((lane >> 4) << 2);  // local s of r=0
#pragma unroll
      for (int nf = 0; nf < 4; ++nf) {
        int dv = wn * 64 + nf * 16 + (lane & 15);        // local dv
        U16x4 o;
        o.x = f2bf(acc[mf][nf][0]);
        o.y = f2bf(acc[mf][nf][1]);
        o.z = f2bf(acc[mf][nf][2]);
        o.w = f2bf(acc[mf][nf][3]);
        *(U16x4*)(T + dv * 136 + sl0) = o;
      }
    }
    __syncthreads();
    // 256 threads: thread handles dv-row tid>>1, s-half (tid&1)*64 (128B).
    int dvl = tid >> 1, sh = (tid & 1) << 6;
    int dvg = (tn - 20) * 128 + dvl;              // global d within [0,512)
    int khl = dvg >> 6, dd = dvg & 63;
    int bb = tm >> 4;                             // block-uniform batch
    int sloc = (tm & 15) * 128 + sh;              // s WITHIN batch (fix: mask!)
    u16* dst = Vt + (size_t)((bb * 8 + khl) * 64 + dd) * 2048 + sloc;
    const u16* srcT = T + dvl * 136 + sh;
#pragma unroll
    for (int j = 0; j < 8; ++j)
      *(u32x4*)(dst + j * 8) = *(const u32x4*)(srcT + j * 8);
  }
}

// ---------------------------------------------------------------------------
// C[M][N] = A[M][K] * BT[N][K]^T  (bf16 in, float out) -- WO GEMM (exact R11).
__global__ __launch_bounds__(256, 2) void gemm_bt(const u16* __restrict__ A,
                                                  const u16* __restrict__ BT,
                                                  float* __restrict__ C,
                                                  int M, int N, int K) {
  __shared__ __align__(16) char smem[65536];
  const int tid = threadIdx.x;
  const int lane = tid & 63;
  const int wm = (tid >> 7) & 1, wn = (tid >> 6) & 1;
  const int tm = blockIdx.y, tn = blockIdx.x;
  const int Kb = K * 2;

  f32x4 acc[4][4];
#pragma unroll
  for (int i = 0; i < 4; ++i)
#pragma unroll
    for (int j = 0; j < 4; ++j) acc[i][j] = (f32x4){0.f, 0.f, 0.f, 0.f};

  const char* Ag = (const char*)A + (size_t)tm * 128 * Kb;
  const char* Bg = (const char*)BT + (size_t)tn * 128 * Kb;

  auto stage = [&](int buf, int t) {
#pragma unroll
    for (int i = 0; i < 4; ++i) {
      int vt = i * 256 + tid;
      int row = vt >> 3;
      int cb = (((vt & 7) << 4) ^ ((row & 7) << 4));
      gload16(Ag + (size_t)row * Kb + t * 128 + cb, smem + buf * 16384 + vt * 16);
      gload16(Bg + (size_t)row * Kb + t * 128 + cb, smem + 32768 + buf * 16384 + vt * 16);
    }
  };

  stage(0, 0);
  int cur = 0;
  const int NT = K >> 6;
  for (int t = 0; t < NT; ++t) {
    __syncthreads();
    if (t + 1 < NT) stage(cur ^ 1, t + 1);
    const char* As = smem + cur * 16384;
    const char* Bs = smem + 32768 + cur * 16384;
#pragma unroll
    for (int ks = 0; ks < 2; ++ks) {
      bf16x8 a[4], b[4];
#pragma unroll
      for (int mf = 0; mf < 4; ++mf) {
        int row = wm * 64 + mf * 16 + (lane & 15);
        int cb = (ks * 64 + ((lane >> 4) << 4)) ^ ((row & 7) << 4);
        a[mf] = *(const bf16x8*)(As + row * 128 + cb);
      }
#pragma unroll
      for (int nf = 0; nf < 4; ++nf) {
        int row = wn * 64 + nf * 16 + (lane & 15);
        int cb = (ks * 64 + ((lane >> 4) << 4)) ^ ((row & 7) << 4);
        b[nf] = *(const bf16x8*)(Bs + row * 128 + cb);
      }
#pragma unroll
      for (int mf = 0; mf < 4; ++mf)
#pragma unroll
        for (int nf = 0; nf < 4; ++nf) acc[mf][nf] = mfma16(a[mf], b[nf], acc[mf][nf]);
    }
    cur ^= 1;
  }
#pragma unroll
  for (int mf = 0; mf < 4; ++mf) {
    int row0 = tm * 128 + wm * 64 + mf * 16 + ((lane >> 4) << 2);
#pragma unroll
    for (int nf = 0; nf < 4; ++nf) {
      int col = tn * 128 + wn * 64 + nf * 16 + (lane & 15);
#pragma unroll
      for (int r = 0; r < 4; ++r)
        C[(size_t)(row0 + r) * N + col] = acc[mf][nf][r];
    }
  }
}

// ---------------------------------------------------------------------------
// Causal GQA flash attention -- EXACT R11 kernel (proven, 75.2 us):
// dual-tile waves, swapped QK^T, in-register P, PV via K=32 MFMA through a
// kv-permuted K tile, KVBLK=32, ones-column MFMA for l, fully resident
// (2048 blocks x 128 thr x 16KB = 8 blocks/CU, perfectly balanced).
__global__ __launch_bounds__(128, 4) void attn(const u16* __restrict__ Q,
                                               const u16* __restrict__ Kt,
                                               const u16* __restrict__ Vt,
                                               u16* __restrict__ O) {
  __shared__ __align__(16) char smem[16384];  // per buf: K 4KB + V 4KB

  const int tid = threadIdx.x, lane = tid & 63, w = tid >> 6;  // w in {0,1}
  const int q15 = lane & 15, g = lane >> 4;
  const int bx = blockIdx.x, h = blockIdx.y, b = blockIdx.z;
  const int kh = h >> 2;
  const int QT0 = 63 - bx, QT1 = bx;  // heavy, light q-tiles (32 rows each)

  const char* Qg = (const char*)(Q + ((size_t)(b * 32 + h) * 2048) * 64);
  const char* Kg = (const char*)(Kt + ((size_t)(b * 8 + kh) * 2048 * 64));
  const char* Vg = (const char*)(Vt + ((size_t)(b * 8 + kh) * 64 * 2048));

  u32x4 onesW;
  onesW.x = onesW.y = onesW.z = onesW.w = 0x3F803F80u;  // bf16 1.0 x8
  const bf16x8 ONES = __builtin_bit_cast(bf16x8, onesW);

  // Q fragments (B-operand of swapped QK^T), both tiles
  bf16x8 qf0[2], qf1[2];
#pragma unroll
  for (int ks = 0; ks < 2; ++ks) {
    int r0 = QT0 * 32 + w * 16 + q15;
    int r1 = QT1 * 32 + w * 16 + q15;
    qf0[ks] = *(const bf16x8*)(Qg + (size_t)r0 * 128 + ks * 64 + (g << 4));
    qf1[ks] = *(const bf16x8*)(Qg + (size_t)r1 * 128 + ks * 64 + (g << 4));
  }

  f32x4 acc0[4], acc1[4], accl0, accl1;
#pragma unroll
  for (int j = 0; j < 4; ++j) {
    acc0[j] = (f32x4){0.f, 0.f, 0.f, 0.f};
    acc1[j] = (f32x4){0.f, 0.f, 0.f, 0.f};
  }
  accl0 = (f32x4){0.f, 0.f, 0.f, 0.f};
  accl1 = (f32x4){0.f, 0.f, 0.f, 0.f};
  float m0 = -1e30f, m1 = -1e30f;
  const f32x4 FZ = (f32x4){0.f, 0.f, 0.f, 0.f};

  auto stageKV = [&](int buf, int kt) {
#pragma unroll
    for (int i = 0; i < 2; ++i) {
      int vt = i * 128 + tid;  // 0..255
      // K: LDS row rho holds global kv row kappa(rho) = 8g'+4nf'+r'
      int rho = vt >> 3, ck = vt & 7;
      int kap = ((rho & 12) << 1) + ((rho & 16) >> 2) + (rho & 3);
      gload16(Kg + (size_t)(kt * 32 + kap) * 128 + (((ck ^ rho) & 7) << 4),
              smem + buf * 8192 + vt * 16);
      // V: natural kv order, 64 d-rows x 64B, chunk swizzle ^((d>>1)&3)
      int d = vt >> 2, cv = vt & 3;
      gload16(Vg + (size_t)d * 4096 + kt * 64 + (((cv ^ (d >> 1)) & 3) << 4),
              smem + buf * 8192 + 4096 + vt * 16);
    }
  };

  stageKV(0, 0);
  int cur = 0;
  const int nkt = QT0 + 1;
  for (int kt = 0; kt < nkt; ++kt) {
    __syncthreads();  // KV[cur] staged (compiler drains vmcnt before barrier)
    if (kt + 1 < nkt) stageKV(cur ^ 1, kt + 1);
    const char* Ks = smem + cur * 8192;
    const char* Vs = smem + cur * 8192 + 4096;
    const bool la = (kt <= QT1);  // light tile active

    // K fragments (A-operand), shared by both tiles
    bf16x8 kf[2][2];  // [ks][nf]
#pragma unroll
    for (int ks = 0; ks < 2; ++ks)
#pragma unroll
      for (int nf = 0; nf < 2; ++nf) {
        int r = nf * 16 + q15;
        int c = (4 * ks + g) ^ (r & 7);
        kf[ks][nf] = *(const bf16x8*)(Ks + r * 128 + (c << 4));
      }

    // swapped QK^T: lane holds S[q = Qt*32+w*16+q15][k = kt*32 + 8g+4nf+r]
    f32x4 st0[2], st1[2];
    __builtin_amdgcn_s_setprio(1);
#pragma unroll
    for (int nf = 0; nf < 2; ++nf) {
      st0[nf] = mfma16(kf[0][nf], qf0[0], FZ);
      st0[nf] = mfma16(kf[1][nf], qf0[1], st0[nf]);
    }
    if (la) {
#pragma unroll
      for (int nf = 0; nf < 2; ++nf) {
        st1[nf] = mfma16(kf[0][nf], qf1[0], FZ);
        st1[nf] = mfma16(kf[1][nf], qf1[1], st1[nf]);
      }
    }
    __builtin_amdgcn_s_setprio(0);

    // causal mask on each tile's diagonal step (k = kt*32 + 8g + 4nf + r)
    if (kt == QT0) {
      int qg = QT0 * 32 + w * 16 + q15;
#pragma unroll
      for (int nf = 0; nf < 2; ++nf)
#pragma unroll
        for (int r = 0; r < 4; ++r) {
          int kg = kt * 32 + 8 * g + 4 * nf + r;
          if (kg > qg) st0[nf][r] = -1e30f;
        }
    }
    if (la && kt == QT1) {
      int qg = QT1 * 32 + w * 16 + q15;
#pragma unroll
      for (int nf = 0; nf < 2; ++nf)
#pragma unroll
        for (int r = 0; r < 4; ++r) {
          int kg = kt * 32 + 8 * g + 4 * nf + r;
          if (kg > qg) st1[nf][r] = -1e30f;
        }
    }

    // softmax (exp2 domain): zero cross-lane ops in the common path; l is
    // accumulated by the ones-column MFMA in the PV step below.
    bf16x8 pa0, pa1;
#pragma unroll
    for (int t = 0; t < 2; ++t) {
      if (t == 1 && !la) break;
      f32x4* st = (t == 0) ? st0 : st1;
      float& m_r = (t == 0) ? m0 : m1;
      f32x4* accT = (t == 0) ? acc0 : acc1;
      f32x4& acclT = (t == 0) ? accl0 : accl1;

      // per-lane max over this lane's 8 S values + m_r, 3-ary for v_max3
      float vm = fmaxf(fmaxf(fmaxf(fmaxf(st[0][0], st[0][1]), st[0][2]),
                             fmaxf(fmaxf(st[0][3], st[1][0]), st[1][1])),
                       fmaxf(fmaxf(st[1][2], st[1][3]), m_r));
      // T13 defer-rescale: __all on per-lane max == check on the global max.
      if (!__all(vm - m_r <= 8.0f)) {
        vm = fmaxf(vm, __shfl_xor(vm, 16, 64));
        vm = fmaxf(vm, __shfl_xor(vm, 32, 64));
        float cr = EXP2(m_r - vm);
        m_r = vm;
        float cra[4];
#pragma unroll
        for (int r = 0; r < 4; ++r) cra[r] = __shfl(cr, 4 * g + r, 64);
#pragma unroll
        for (int nfd = 0; nfd < 4; ++nfd)
#pragma unroll
          for (int r = 0; r < 4; ++r) accT[nfd][r] *= cra[r];
#pragma unroll
        for (int r = 0; r < 4; ++r) acclT[r] *= cra[r];
      }
      // P = exp2(S - m); pack into the K=32 A-fragment (k = 8g + 4nf + r)
      u32x4 W;
      W.x = pk2bf(EXP2(st[0][0] - m_r), EXP2(st[0][1] - m_r));
      W.y = pk2bf(EXP2(st[0][2] - m_r), EXP2(st[0][3] - m_r));
      W.z = pk2bf(EXP2(st[1][0] - m_r), EXP2(st[1][1] - m_r));
      W.w = pk2bf(EXP2(st[1][2] - m_r), EXP2(st[1][3] - m_r));
      if (t == 0) pa0 = __builtin_bit_cast(bf16x8, W);
      else pa1 = __builtin_bit_cast(bf16x8, W);
    }

    // PV via K=32 MFMA: B-frag = V^T[d = nfd*16+q15][k = kt*32 + 8g..8g+7];
    // plus one ones-column MFMA per tile to accumulate l in acc layout.
#pragma unroll
    for (int nfd = 0; nfd < 4; ++nfd) {
      int d = nfd * 16 + q15;
      int c = (g ^ (d >> 1)) & 3;
      bf16x8 vb = *(const bf16x8*)(Vs + d * 64 + (c << 4));
      __builtin_amdgcn_s_setprio(1);
      acc0[nfd] = mfma16(pa0, vb, acc0[nfd]);
      if (la) acc1[nfd] = mfma16(pa1, vb, acc1[nfd]);
      __builtin_amdgcn_s_setprio(0);
    }
    __builtin_amdgcn_s_setprio(1);
    accl0 = mfma16(pa0, ONES, accl0);
    if (la) accl1 = mfma16(pa1, ONES, accl1);
    __builtin_amdgcn_s_setprio(0);
    cur ^= 1;
  }

  // epilogue: l is already per-lane in acc row layout -- no shuffles.
#pragma unroll
  for (int t = 0; t < 2; ++t) {
    f32x4* accT = (t == 0) ? acc0 : acc1;
    f32x4 acclT = (t == 0) ? accl0 : accl1;
    int qt = (t == 0) ? QT0 : QT1;
    u16* Og = O + ((size_t)(b * 2048 + qt * 32 + w * 16) * 2048 + h * 64);
#pragma unroll
    for (int r = 0; r < 4; ++r) {
      float li = 1.f / acclT[r];
#pragma unroll
      for (int nfd = 0; nfd < 4; ++nfd)
        Og[(size_t)(4 * g + r) * 2048 + nfd * 16 + q15] = f2bf(accT[nfd][r] * li);
    }
  }
}

// ---------------------------------------------------------------------------
extern "C" void kernel_launch(void* const* d_in, const int* in_sizes, int n_in,
                              void* d_out, int out_size, void* d_ws, size_t ws_size,
                              hipStream_t stream) {
  const float* x = (const float*)d_in[0];
  const float* fc = (const float*)d_in[1];
  const float* fs = (const float*)d_in[2];
  const float* wq = (const float*)d_in[3];
  const float* wk = (const float*)d_in[4];
  const float* wv = (const float*)d_in[5];
  const float* wo = (const float*)d_in[6];
  float* out = (float*)d_out;
  char* ws = (char*)d_ws;

  // Workspace layout (64 MB):
  u16* xb    = (u16*)(ws);                 // [4096][2048] 16 MB (reused as attn O)
  u16* Qb    = (u16*)(ws + 16777216);      // [2][32][2048][64] 16 MB (roped, exp2-scaled)
  u16* Kb    = (u16*)(ws + 33554432);      // [2][8][2048][64]   4 MB (roped)
  u16* Vtb   = (u16*)(ws + 41943040);      // [2][8][64][2048]   4 MB (written by gemm_qkv)
  u16* woT   = (u16*)(ws + 46137344);      // [2048][2048]       8 MB
  u16* wqkvT = (u16*)(ws + 54525952);      // [3072][2048]      12 MB
  u16* Obuf = xb;

  dim3 tb(32, 8);
  prep<<<dim3(18432), tb, 0, stream>>>(x, wq, wk, wv, wo, xb, wqkvT, woT);
  gemm_qkv<<<dim3(24, 32), dim3(256), 0, stream>>>(xb, wqkvT, fc, fs, Qb, Kb, Vtb);
  attn<<<dim3(32, 32, 2), dim3(128), 0, stream>>>(Qb, Kb, Vtb, Obuf);
  gemm_bt<<<dim3(16, 32), dim3(256), 0, stream>>>(Obuf, woT, out, 4096, 2048, 2048);
}